// Round 1
// 378.171 us; speedup vs baseline: 1.0895x; 1.0895x over previous
//
#include <hip/hip_runtime.h>
#include <cmath>

// b=4, c=512, h=w=64 -> n=4096, groups=32 (16 ch/group)
#define NB 4
#define NC 512
#define NN 4096
#define ATTN_SCALE 0.04419417382415922f  // 512^-0.5

typedef __bf16 bf16x8 __attribute__((ext_vector_type(8)));
typedef float floatx4 __attribute__((ext_vector_type(4)));

__device__ __forceinline__ unsigned short f2bf(float f) {
    union { float f; unsigned int u; } v; v.f = f;
    return (unsigned short)((v.u + 0x7fffu + ((v.u >> 16) & 1u)) >> 16);
}
__device__ __forceinline__ unsigned short f2bf_trunc(float f) {
    union { float f; unsigned int u; } v; v.f = f;
    return (unsigned short)(v.u >> 16);
}
__device__ __forceinline__ float bf2f(unsigned short u) {
    union { unsigned int u; float f; } v; v.u = ((unsigned int)u) << 16;
    return v.f;
}

__device__ __forceinline__ void gload_lds16(const unsigned short* gp, unsigned short* lp) {
    __builtin_amdgcn_global_load_lds(
        (const __attribute__((address_space(1))) void*)gp,
        (__attribute__((address_space(3))) void*)lp, 16, 0, 0);
}

// ---------------------------------------------------------------------------
// Kernel 1a: GroupNorm partial sums. 1024 blocks = (b,g) x 8 slices.
// ---------------------------------------------------------------------------
__global__ __launch_bounds__(256) void gn_partial_kernel(
    const float* __restrict__ x, float* __restrict__ part)
{
    int blk = blockIdx.x;
    int bg = blk >> 3, sub = blk & 7;
    const float4* xv = (const float4*)(x + (size_t)bg * 16 * NN + (size_t)sub * 8192);
    float s1 = 0.f, s2 = 0.f;
#pragma unroll
    for (int i = 0; i < 8; ++i) {
        float4 v = xv[threadIdx.x + i * 256];
        s1 += v.x + v.y + v.z + v.w;
        s2 += v.x * v.x + v.y * v.y + v.z * v.z + v.w * v.w;
    }
#pragma unroll
    for (int off = 32; off; off >>= 1) {
        s1 += __shfl_xor(s1, off, 64);
        s2 += __shfl_xor(s2, off, 64);
    }
    __shared__ float r1[4], r2[4];
    int lane = threadIdx.x & 63, w = threadIdx.x >> 6;
    if (lane == 0) { r1[w] = s1; r2[w] = s2; }
    __syncthreads();
    if (threadIdx.x == 0) {
        part[blk * 2]     = r1[0] + r1[1] + r1[2] + r1[3];
        part[blk * 2 + 1] = r2[0] + r2[1] + r2[2] + r2[3];
    }
}

// Kernel 1b: finalize -> per-channel scale/shift
__global__ __launch_bounds__(128) void gn_final_kernel(
    const float* __restrict__ part, const float* __restrict__ gw,
    const float* __restrict__ gb, float* __restrict__ ss)
{
    int tg = threadIdx.x;            // 0..127 = b*32+g
    int b = tg >> 5, g = tg & 31;
    float s1 = 0.f, s2 = 0.f;
#pragma unroll
    for (int s = 0; s < 8; ++s) {
        s1 += part[(tg * 8 + s) * 2];
        s2 += part[(tg * 8 + s) * 2 + 1];
    }
    float mean = s1 * (1.0f / 65536.0f);
    float var  = s2 * (1.0f / 65536.0f) - mean * mean;
    float rstd = rsqrtf(var + 1e-5f);
#pragma unroll
    for (int i = 0; i < 16; ++i) {
        int c = g * 16 + i;
        float sc = rstd * gw[c];
        ss[b * NC + c] = sc;
        ss[2048 + b * NC + c] = gb[c] - mean * sc;
    }
}

// ---------------------------------------------------------------------------
// Kernel 2: convert weights fp32 -> bf16
// ---------------------------------------------------------------------------
__global__ __launch_bounds__(256) void wconv_kernel(
    const float* __restrict__ qkv_w, const float* __restrict__ out_w,
    unsigned short* __restrict__ wq, unsigned short* __restrict__ wo)
{
    int i = blockIdx.x * 256 + threadIdx.x;
    const int NQ = 1536 * 512;
    if (i < NQ) wq[i] = f2bf(qkv_w[i]);
    else        wo[i - NQ] = f2bf(out_w[i - NQ]);
}

// ---------------------------------------------------------------------------
// Kernel 3: normalize + transpose: x (b,c,n) fp32 -> h_t (b,n,c) bf16
// ---------------------------------------------------------------------------
__global__ __launch_bounds__(256) void htnorm_kernel(
    const float* __restrict__ x, const float* __restrict__ ss,
    unsigned short* __restrict__ ht)
{
    int b = blockIdx.z;
    int c0 = blockIdx.y * 32, n0 = blockIdx.x * 32;
    __shared__ float T[32][33];
    int tx = threadIdx.x & 31, ty = threadIdx.x >> 5;   // ty 0..7
    const float* xb = x + ((size_t)b * NC + c0) * NN;
    const float* sc = ss + b * NC + c0;
    const float* sh = ss + 2048 + b * NC + c0;
#pragma unroll
    for (int i = 0; i < 4; ++i) {
        int c = ty + i * 8;
        T[c][tx] = xb[(size_t)c * NN + n0 + tx] * sc[c] + sh[c];
    }
    __syncthreads();
    unsigned short* hb = ht + ((size_t)b * NN + n0) * NC + c0;
#pragma unroll
    for (int i = 0; i < 4; ++i) {
        int n = ty + i * 8;
        hb[(size_t)n * NC + tx] = f2bf(T[tx][n]);
    }
}

// ---------------------------------------------------------------------------
// MFMA NT GEMM: C[m,n] = sum_k A[m,k]*B[n,k], BMxBN block tile, BK=32.
// MODE 0: qkv q/k   M=4096 N=1024 K=512  A=ht(+z) B=wqk    -> qt(*scale)/kt +bias
// MODE 1: qkv v     M=512  N=4096 K=512  A=wv     B=ht(+z) -> vt (c,p) bf16 +bias
// MODE 2: QK^T      M=4096 N=4096 K=512  A=qt(+z) B=kt(+z) -> SP = exp(s) bf16,
//                   row-sums atomically accumulated into outf = L[b*NN+row]
// MODE 4: out proj  M=512  N=4096 K=512  A=wo     B=Ob(+z) -> out fp32 +bias+res
// ---------------------------------------------------------------------------
template<int MODE, int BM, int BN>
__global__ __launch_bounds__(256, 3) void mfma_gemm(
    const unsigned short* __restrict__ Abase,
    const unsigned short* __restrict__ Bbase,
    const float* __restrict__ e0, const float* __restrict__ e1,
    float* __restrict__ outf,
    unsigned short* __restrict__ ob0, unsigned short* __restrict__ ob1)
{
    constexpr int K = 512;
    constexpr int FI = BM / 32;       // frag rows per wave
    constexpr int FJ = BN / 32;       // frag cols per wave
    const int z = blockIdx.z;
    const size_t bnc = (size_t)NN * NC;
    const size_t bss = (size_t)NN * NN;

    const unsigned short* A;
    const unsigned short* B;
    if constexpr (MODE == 0)      { A = Abase + (size_t)z * bnc; B = Bbase; }
    else if constexpr (MODE == 1) { A = Abase; B = Bbase + (size_t)z * bnc; }
    else if constexpr (MODE == 2) { A = Abase + (size_t)z * bnc; B = Bbase + (size_t)z * bnc; }
    else                          { A = Abase; B = Bbase + (size_t)z * bnc; }

    const int m0 = blockIdx.y * BM;
    const int n0 = blockIdx.x * BN;

    __shared__ __attribute__((aligned(16))) unsigned short As[BM * 32];
    __shared__ __attribute__((aligned(16))) unsigned short Bs[BN * 32];

    const int t = threadIdx.x;
    const int lane = t & 63;
    const int w = t >> 6;
    const int wr = w >> 1, wc = w & 1;

    const int sr = w * 16 + (lane >> 2);       // staging row within 64-row slab
    const int sc8 = (lane & 3) * 8;            // element offset within 32
    const int lds_elem = w * 512;

    floatx4 acc[FI][FJ] = {};

    for (int k0 = 0; k0 < K; k0 += 32) {
#pragma unroll
        for (int s = 0; s < BM / 64; ++s)
            gload_lds16(A + (size_t)(m0 + s * 64 + sr) * K + k0 + sc8,
                        As + s * 2048 + lds_elem);
#pragma unroll
        for (int s = 0; s < BN / 64; ++s)
            gload_lds16(B + (size_t)(n0 + s * 64 + sr) * K + k0 + sc8,
                        Bs + s * 2048 + lds_elem);
        __syncthreads();

        bf16x8 af[FI], bfr[FJ];
        const unsigned short* Ab = As + ((wr * (BM / 2) + (lane & 15)) * 32) + (lane >> 4) * 8;
        const unsigned short* Bb = Bs + ((wc * (BN / 2) + (lane & 15)) * 32) + (lane >> 4) * 8;
#pragma unroll
        for (int i = 0; i < FI; ++i) af[i]  = *(const bf16x8*)(Ab + i * 16 * 32);
#pragma unroll
        for (int j = 0; j < FJ; ++j) bfr[j] = *(const bf16x8*)(Bb + j * 16 * 32);
#pragma unroll
        for (int i = 0; i < FI; ++i)
#pragma unroll
            for (int j = 0; j < FJ; ++j)
                acc[i][j] = __builtin_amdgcn_mfma_f32_16x16x32_bf16(
                    af[i], bfr[j], acc[i][j], 0, 0, 0);
        __syncthreads();
    }

    // Epilogue. C/D: col = lane&15, row = (lane>>4)*4 + reg
    const int fr = lane >> 4;
    const int fc = lane & 15;

    if constexpr (MODE == 2) {
        // exp + truncated bf16 store + per-row sum (16-lane reduce + atomicAdd)
        float rs[FI][4];
#pragma unroll
        for (int i = 0; i < FI; ++i)
#pragma unroll
            for (int r = 0; r < 4; ++r) rs[i][r] = 0.f;
#pragma unroll
        for (int i = 0; i < FI; ++i) {
#pragma unroll
            for (int j = 0; j < FJ; ++j) {
                int n = n0 + wc * (BN / 2) + j * 16 + fc;
                int mbase = m0 + wr * (BM / 2) + i * 16 + fr * 4;
#pragma unroll
                for (int r = 0; r < 4; ++r) {
                    float e = __expf(acc[i][j][r]);
                    ob0[(size_t)z * bss + (size_t)(mbase + r) * NN + n] = f2bf_trunc(e);
                    rs[i][r] += e;
                }
            }
        }
#pragma unroll
        for (int i = 0; i < FI; ++i) {
#pragma unroll
            for (int r = 0; r < 4; ++r) {
                float v = rs[i][r];
                v += __shfl_xor(v, 1, 16);
                v += __shfl_xor(v, 2, 16);
                v += __shfl_xor(v, 4, 16);
                v += __shfl_xor(v, 8, 16);
                if (fc == 0) {
                    int m = m0 + wr * (BM / 2) + i * 16 + fr * 4 + r;
                    atomicAdd(&outf[z * NN + m], v);
                }
            }
        }
        return;
    }

#pragma unroll
    for (int i = 0; i < FI; ++i) {
#pragma unroll
        for (int j = 0; j < FJ; ++j) {
            int n = n0 + wc * (BN / 2) + j * 16 + fc;
            int mbase = m0 + wr * (BM / 2) + i * 16 + fr * 4;
#pragma unroll
            for (int r = 0; r < 4; ++r) {
                int m = mbase + r;
                float val = acc[i][j][r];
                if constexpr (MODE == 0) {
                    val += e0[n];   // qkv bias, o = n in [0,1024)
                    if (n < 512) ob0[((size_t)z * NN + m) * NC + n] = f2bf(val * ATTN_SCALE);
                    else         ob1[((size_t)z * NN + m) * NC + (n - 512)] = f2bf(val);
                } else if constexpr (MODE == 1) {
                    val += e0[1024 + m];   // v bias, channel = m
                    ob0[((size_t)z * NC + m) * NN + n] = f2bf(val);
                } else {   // MODE 4
                    size_t idx = ((size_t)z * NC + m) * NN + n;
                    outf[idx] = val + e0[m] + e1[idx];
                }
            }
        }
    }
}

// ---------------------------------------------------------------------------
// PV GEMM: O[p,c] = (sum_m P[p,m] * V[m,c]) / L[p]
// Rework vs previous version (which was latency-bound: 512 blocks = 2/CU,
// MfmaUtil 21%, Occupancy 22%, 1e7 LDS bank-conflict cycles):
//   - BM=64 x BN=128 -> 1024 blocks = 4 blocks/CU (launch_bounds(256,4))
//   - BK=64 -> 64 K-steps (half the barriers), 16 MFMA per step per wave
//   - XOR-swizzled LDS (rule 21: linear gload_lds dest + pre-swizzled global
//     source col + swizzled ds_read addr). Row stride is 128B; swizzle
//     slot^=(row&7) spreads the 16 fragment lanes over 8 slots = 2-way = free.
//   - XCD-aware 1-D block decode: the 4 c-tile siblings of each (z,ptile)
//     pair are consecutive on one XCD -> SP slab (512KB) is L2-hit 3/4 times
//     despite the x4 logical re-read at BN=128.
// ---------------------------------------------------------------------------
__global__ __launch_bounds__(256, 4) void pv_gemm(
    const unsigned short* __restrict__ Abase,
    const unsigned short* __restrict__ Bbase,
    const float* __restrict__ L,
    unsigned short* __restrict__ Ob)
{
    // id -> (xcd, j); same-XCD ids are spaced 8 apart. c cycles fastest.
    const int id = blockIdx.x;
    const int xcd = id & 7;
    const int j0 = id >> 3;
    const int ct = j0 & 3;          // c-tile 0..3
    const int pairl = j0 >> 2;      // 0..31 per XCD
    const int p = pairl * 8 + xcd;  // 0..255 bijective
    const int ptile = p & 63, z = p >> 6;

    const size_t bss = (size_t)NN * NN, bnc = (size_t)NN * NC;
    const unsigned short* A = Abase + (size_t)z * bss;   // SP: (p, m)
    const unsigned short* B = Bbase + (size_t)z * bnc;   // V^T: (c, m)
    const int m0 = ptile * 64;
    const int n0 = ct * 128;

    __shared__ __attribute__((aligned(16))) unsigned short As[64 * 64];    // 8 KB
    __shared__ __attribute__((aligned(16))) unsigned short Bs[128 * 64];   // 16 KB

    const int t = threadIdx.x;
    const int lane = t & 63;
    const int w = t >> 6;
    const int wr = w >> 1, wc = w & 1;

    // staging: one gload round = 256 threads x 16B = 32 rows x 64 cols.
    // row&7 == lane>>3, so the pre-swizzled source slot is wave-invariant.
    const int sr = w * 8 + (lane >> 3);
    const int scs = ((lane & 7) ^ (lane >> 3)) * 8;   // pre-swizzled col (elems)
    const int lds_elem = w * 512;

    floatx4 acc[2][4] = {};

    for (int k0 = 0; k0 < NN; k0 += 64) {
#pragma unroll
        for (int s = 0; s < 2; ++s)
            gload_lds16(A + (size_t)(m0 + s * 32 + sr) * NN + k0 + scs,
                        As + s * 2048 + lds_elem);
#pragma unroll
        for (int s = 0; s < 4; ++s)
            gload_lds16(B + (size_t)(n0 + s * 32 + sr) * NN + k0 + scs,
                        Bs + s * 2048 + lds_elem);
        __syncthreads();

        bf16x8 af[2][2], bfr[4][2];
#pragma unroll
        for (int i = 0; i < 2; ++i) {
            const int ra = wr * 32 + i * 16 + (lane & 15);
#pragma unroll
            for (int kk = 0; kk < 2; ++kk)
                af[i][kk] = *(const bf16x8*)(As + ra * 64 +
                    (((kk * 4 + (lane >> 4)) ^ (ra & 7)) * 8));
        }
#pragma unroll
        for (int jj = 0; jj < 4; ++jj) {
            const int rb = wc * 64 + jj * 16 + (lane & 15);
#pragma unroll
            for (int kk = 0; kk < 2; ++kk)
                bfr[jj][kk] = *(const bf16x8*)(Bs + rb * 64 +
                    (((kk * 4 + (lane >> 4)) ^ (rb & 7)) * 8));
        }
#pragma unroll
        for (int kk = 0; kk < 2; ++kk)
#pragma unroll
            for (int i = 0; i < 2; ++i)
#pragma unroll
                for (int jj = 0; jj < 4; ++jj)
                    acc[i][jj] = __builtin_amdgcn_mfma_f32_16x16x32_bf16(
                        af[i][kk], bfr[jj][kk], acc[i][jj], 0, 0, 0);
        __syncthreads();
    }

    const int fr = lane >> 4;
    const int fc = lane & 15;
#pragma unroll
    for (int i = 0; i < 2; ++i) {
#pragma unroll
        for (int r = 0; r < 4; ++r) {
            int m = m0 + wr * 32 + i * 16 + fr * 4 + r;
            float linv = 1.0f / L[z * NN + m];
#pragma unroll
            for (int jj = 0; jj < 4; ++jj) {
                int n = n0 + wc * 64 + jj * 16 + fc;
                Ob[(size_t)z * bnc + (size_t)m * NC + n] = f2bf(acc[i][jj][r] * linv);
            }
        }
    }
}

// ---------------------------------------------------------------------------
extern "C" void kernel_launch(void* const* d_in, const int* in_sizes, int n_in,
                              void* d_out, int out_size, void* d_ws, size_t ws_size,
                              hipStream_t stream)
{
    const float* x     = (const float*)d_in[0];
    const float* gn_w  = (const float*)d_in[1];
    const float* gn_b  = (const float*)d_in[2];
    const float* qkv_w = (const float*)d_in[3];
    const float* qkv_b = (const float*)d_in[4];
    const float* out_w = (const float*)d_in[5];
    const float* out_b = (const float*)d_in[6];
    float* out = (float*)d_out;

    const size_t bnc = (size_t)NN * NC;          // 2,097,152 per batch
    char* w = (char*)d_ws;
    float* ss   = (float*)w;                 w += 16384;
    float* part = (float*)w;                 w += 8192;
    float* Lsum = (float*)w;                 w += (size_t)NB * NN * 4;  // row sums
    unsigned short* wq = (unsigned short*)w; w += (size_t)1536 * 512 * 2;
    unsigned short* wo = (unsigned short*)w; w += (size_t)512 * 512 * 2;
    unsigned short* qt = (unsigned short*)w; w += NB * bnc * 2;   // (b,n,c) pre-scaled
    unsigned short* kt = (unsigned short*)w; w += NB * bnc * 2;   // (b,n,c)
    unsigned short* vt = (unsigned short*)w; w += NB * bnc * 2;   // (b,c,n)
    unsigned short* SP = (unsigned short*)w; w += (size_t)NB * NN * NN * 2; // 128 MB
    // Aliases (lifetime-disjoint):
    unsigned short* ht = SP;   // ht (b,n,c) dead before MODE 2 writes SP
    unsigned short* Ob = qt;   // Ob (b,n,c) written after qt last read (MODE 2)

    hipMemsetAsync(Lsum, 0, (size_t)NB * NN * sizeof(float), stream);

    gn_partial_kernel<<<1024, 256, 0, stream>>>(x, part);
    gn_final_kernel<<<1, 128, 0, stream>>>(part, gn_w, gn_b, ss);
    wconv_kernel<<<(1536 * 512 + 512 * 512) / 256, 256, 0, stream>>>(qkv_w, out_w, wq, wo);
    htnorm_kernel<<<dim3(NN / 32, NC / 32, NB), 256, 0, stream>>>(x, ss, ht);

    // q/k: C[p,o] = ht · wqk^T   (q pre-scaled by ATTN_SCALE)
    mfma_gemm<0, 128, 128><<<dim3(1024 / 128, NN / 128, NB), 256, 0, stream>>>(
        ht, wq, qkv_b, nullptr, nullptr, qt, kt);
    // v: C[c,p] = wv · ht^T
    mfma_gemm<1, 128, 128><<<dim3(NN / 128, 512 / 128, NB), 256, 0, stream>>>(
        wq + (size_t)1024 * 512, ht, qkv_b, nullptr, nullptr, vt, nullptr);

    // QK^T + exp + row-sum accumulation, all batches, one dispatch
    mfma_gemm<2, 128, 128><<<dim3(NN / 128, NN / 128, NB), 256, 0, stream>>>(
        qt, kt, nullptr, nullptr, Lsum, SP, nullptr);
    // PV + normalize, all batches, 1024 blocks (XCD-decoded inside)
    pv_gemm<<<dim3(1024), 256, 0, stream>>>(SP, vt, Lsum, Ob);

    // out projection + bias + residual
    mfma_gemm<4, 128, 128><<<dim3(NN / 128, 512 / 128, NB), 256, 0, stream>>>(
        wo, Ob, out_b, x, out, nullptr, nullptr);
}

// Round 2
// 377.611 us; speedup vs baseline: 1.0912x; 1.0015x over previous
//
#include <hip/hip_runtime.h>
#include <cmath>

// b=4, c=512, h=w=64 -> n=4096, groups=32 (16 ch/group)
#define NB 4
#define NC 512
#define NN 4096
#define ATTN_SCALE 0.04419417382415922f  // 512^-0.5

typedef __bf16 bf16x8 __attribute__((ext_vector_type(8)));
typedef float floatx4 __attribute__((ext_vector_type(4)));

__device__ __forceinline__ unsigned short f2bf(float f) {
    union { float f; unsigned int u; } v; v.f = f;
    return (unsigned short)((v.u + 0x7fffu + ((v.u >> 16) & 1u)) >> 16);
}
__device__ __forceinline__ unsigned short f2bf_trunc(float f) {
    union { float f; unsigned int u; } v; v.f = f;
    return (unsigned short)(v.u >> 16);
}
__device__ __forceinline__ float bf2f(unsigned short u) {
    union { unsigned int u; float f; } v; v.u = ((unsigned int)u) << 16;
    return v.f;
}

__device__ __forceinline__ void gload_lds16(const unsigned short* gp, unsigned short* lp) {
    __builtin_amdgcn_global_load_lds(
        (const __attribute__((address_space(1))) void*)gp,
        (__attribute__((address_space(3))) void*)lp, 16, 0, 0);
}

// ---------------------------------------------------------------------------
// Kernel 1a: GroupNorm partial sums. 1024 blocks = (b,g) x 8 slices.
// ---------------------------------------------------------------------------
__global__ __launch_bounds__(256) void gn_partial_kernel(
    const float* __restrict__ x, float* __restrict__ part)
{
    int blk = blockIdx.x;
    int bg = blk >> 3, sub = blk & 7;
    const float4* xv = (const float4*)(x + (size_t)bg * 16 * NN + (size_t)sub * 8192);
    float s1 = 0.f, s2 = 0.f;
#pragma unroll
    for (int i = 0; i < 8; ++i) {
        float4 v = xv[threadIdx.x + i * 256];
        s1 += v.x + v.y + v.z + v.w;
        s2 += v.x * v.x + v.y * v.y + v.z * v.z + v.w * v.w;
    }
#pragma unroll
    for (int off = 32; off; off >>= 1) {
        s1 += __shfl_xor(s1, off, 64);
        s2 += __shfl_xor(s2, off, 64);
    }
    __shared__ float r1[4], r2[4];
    int lane = threadIdx.x & 63, w = threadIdx.x >> 6;
    if (lane == 0) { r1[w] = s1; r2[w] = s2; }
    __syncthreads();
    if (threadIdx.x == 0) {
        part[blk * 2]     = r1[0] + r1[1] + r1[2] + r1[3];
        part[blk * 2 + 1] = r2[0] + r2[1] + r2[2] + r2[3];
    }
}

// Kernel 1b: finalize -> per-channel scale/shift
__global__ __launch_bounds__(128) void gn_final_kernel(
    const float* __restrict__ part, const float* __restrict__ gw,
    const float* __restrict__ gb, float* __restrict__ ss)
{
    int tg = threadIdx.x;            // 0..127 = b*32+g
    int b = tg >> 5, g = tg & 31;
    float s1 = 0.f, s2 = 0.f;
#pragma unroll
    for (int s = 0; s < 8; ++s) {
        s1 += part[(tg * 8 + s) * 2];
        s2 += part[(tg * 8 + s) * 2 + 1];
    }
    float mean = s1 * (1.0f / 65536.0f);
    float var  = s2 * (1.0f / 65536.0f) - mean * mean;
    float rstd = rsqrtf(var + 1e-5f);
#pragma unroll
    for (int i = 0; i < 16; ++i) {
        int c = g * 16 + i;
        float sc = rstd * gw[c];
        ss[b * NC + c] = sc;
        ss[2048 + b * NC + c] = gb[c] - mean * sc;
    }
}

// ---------------------------------------------------------------------------
// Kernel 2: convert weights fp32 -> bf16
// ---------------------------------------------------------------------------
__global__ __launch_bounds__(256) void wconv_kernel(
    const float* __restrict__ qkv_w, const float* __restrict__ out_w,
    unsigned short* __restrict__ wq, unsigned short* __restrict__ wo)
{
    int i = blockIdx.x * 256 + threadIdx.x;
    const int NQ = 1536 * 512;
    if (i < NQ) wq[i] = f2bf(qkv_w[i]);
    else        wo[i - NQ] = f2bf(out_w[i - NQ]);
}

// ---------------------------------------------------------------------------
// Kernel 3: normalize + transpose: x (b,c,n) fp32 -> h_t (b,n,c) bf16
// ---------------------------------------------------------------------------
__global__ __launch_bounds__(256) void htnorm_kernel(
    const float* __restrict__ x, const float* __restrict__ ss,
    unsigned short* __restrict__ ht)
{
    int b = blockIdx.z;
    int c0 = blockIdx.y * 32, n0 = blockIdx.x * 32;
    __shared__ float T[32][33];
    int tx = threadIdx.x & 31, ty = threadIdx.x >> 5;   // ty 0..7
    const float* xb = x + ((size_t)b * NC + c0) * NN;
    const float* sc = ss + b * NC + c0;
    const float* sh = ss + 2048 + b * NC + c0;
#pragma unroll
    for (int i = 0; i < 4; ++i) {
        int c = ty + i * 8;
        T[c][tx] = xb[(size_t)c * NN + n0 + tx] * sc[c] + sh[c];
    }
    __syncthreads();
    unsigned short* hb = ht + ((size_t)b * NN + n0) * NC + c0;
#pragma unroll
    for (int i = 0; i < 4; ++i) {
        int n = ty + i * 8;
        hb[(size_t)n * NC + tx] = f2bf(T[tx][n]);
    }
}

// ---------------------------------------------------------------------------
// MFMA NT GEMM: C[m,n] = sum_k A[m,k]*B[n,k], BMxBN block tile, BK=32.
// Round-2 rework (MODE2 was 124us @ MfmaUtil 23%, 8.4M LDS-conflict cycles,
// fully-exposed global latency: stage -> drain -> compute each K-step):
//   - T3-min double-buffer: stage(next tile) issued BEFORE compute(cur);
//     ONE vmcnt(0)+barrier per K-step (was 2 barriers + exposed latency).
//   - T2 XOR swizzle: LDS slot' = slot ^ ((row>>1)&3). Row stride 64B;
//     (row>>1) (NOT row&3: slot and row parity stay correlated) spreads the
//     16 fragment lanes over 8 distinct 16B slots = 2-way = free (m136).
//     Rule 21: linear gload_lds dest + pre-swizzled global source col
//     ((lane&3)^((lane>>3)&3)) + same XOR on the ds_read address.
//   - MINB template param: MODE 1/4 (M=512) retiled to 64x128 -> 1024
//     blocks = 4 blocks/CU (was 512 blocks = 2/CU).
// MODE 0: qkv q/k   M=4096 N=1024 K=512  A=ht(+z) B=wqk    -> qt(*scale)/kt +bias
// MODE 1: qkv v     M=512  N=4096 K=512  A=wv     B=ht(+z) -> vt (c,p) bf16 +bias
// MODE 2: QK^T      M=4096 N=4096 K=512  A=qt(+z) B=kt(+z) -> SP = exp(s) bf16,
//                   row-sums atomically accumulated into outf = L[b*NN+row]
// MODE 4: out proj  M=512  N=4096 K=512  A=wo     B=Ob(+z) -> out fp32 +bias+res
// ---------------------------------------------------------------------------
template<int MODE, int BM, int BN, int MINB>
__global__ __launch_bounds__(256, MINB) void mfma_gemm(
    const unsigned short* __restrict__ Abase,
    const unsigned short* __restrict__ Bbase,
    const float* __restrict__ e0, const float* __restrict__ e1,
    float* __restrict__ outf,
    unsigned short* __restrict__ ob0, unsigned short* __restrict__ ob1)
{
    constexpr int K = 512;
    constexpr int NT = K / 32;        // 16 K-steps
    constexpr int FI = BM / 32;       // frag rows per wave
    constexpr int FJ = BN / 32;       // frag cols per wave
    const int z = blockIdx.z;
    const size_t bnc = (size_t)NN * NC;
    const size_t bss = (size_t)NN * NN;

    const unsigned short* A;
    const unsigned short* B;
    if constexpr (MODE == 0)      { A = Abase + (size_t)z * bnc; B = Bbase; }
    else if constexpr (MODE == 1) { A = Abase; B = Bbase + (size_t)z * bnc; }
    else if constexpr (MODE == 2) { A = Abase + (size_t)z * bnc; B = Bbase + (size_t)z * bnc; }
    else                          { A = Abase; B = Bbase + (size_t)z * bnc; }

    const int m0 = blockIdx.y * BM;
    const int n0 = blockIdx.x * BN;

    __shared__ __attribute__((aligned(16))) unsigned short As[2][BM * 32];
    __shared__ __attribute__((aligned(16))) unsigned short Bs[2][BN * 32];

    const int t = threadIdx.x;
    const int lane = t & 63;
    const int w = t >> 6;
    const int wr = w >> 1, wc = w & 1;

    // staging: one gload round = 256 threads x 16B = 64 rows x 32 cols.
    const int sr = w * 16 + (lane >> 2);                    // row in 64-row slab
    const int scs = ((lane & 3) ^ ((lane >> 3) & 3)) * 8;   // pre-swizzled col
    const int lds_elem = w * 512;
    const int kslot = lane >> 4;

    floatx4 acc[FI][FJ] = {};

    auto stage = [&](int buf, int k0) {
#pragma unroll
        for (int s = 0; s < BM / 64; ++s)
            gload_lds16(A + (size_t)(m0 + s * 64 + sr) * K + k0 + scs,
                        &As[buf][s * 2048 + lds_elem]);
#pragma unroll
        for (int s = 0; s < BN / 64; ++s)
            gload_lds16(B + (size_t)(n0 + s * 64 + sr) * K + k0 + scs,
                        &Bs[buf][s * 2048 + lds_elem]);
    };

    auto compute = [&](int buf) {
        bf16x8 af[FI], bfr[FJ];
#pragma unroll
        for (int i = 0; i < FI; ++i) {
            const int ra = wr * (BM / 2) + i * 16 + (lane & 15);
            af[i] = *(const bf16x8*)(&As[buf][ra * 32 + ((kslot ^ ((ra >> 1) & 3)) * 8)]);
        }
#pragma unroll
        for (int j = 0; j < FJ; ++j) {
            const int rb = wc * (BN / 2) + j * 16 + (lane & 15);
            bfr[j] = *(const bf16x8*)(&Bs[buf][rb * 32 + ((kslot ^ ((rb >> 1) & 3)) * 8)]);
        }
#pragma unroll
        for (int i = 0; i < FI; ++i)
#pragma unroll
            for (int j = 0; j < FJ; ++j)
                acc[i][j] = __builtin_amdgcn_mfma_f32_16x16x32_bf16(
                    af[i], bfr[j], acc[i][j], 0, 0, 0);
    };

    stage(0, 0);
    asm volatile("s_waitcnt vmcnt(0)" ::: "memory");
    __syncthreads();
    int cur = 0;
    for (int kt = 0; kt < NT - 1; ++kt) {
        stage(cur ^ 1, (kt + 1) * 32);     // prefetch next tile (async)
        compute(cur);                      // hide prefetch under ds_read+MFMA
        asm volatile("s_waitcnt vmcnt(0)" ::: "memory");
        __syncthreads();
        cur ^= 1;
    }
    compute(cur);

    // Epilogue. C/D: col = lane&15, row = (lane>>4)*4 + reg
    const int fr = lane >> 4;
    const int fc = lane & 15;

    if constexpr (MODE == 2) {
        // exp + truncated bf16 store + per-row sum (16-lane reduce + atomicAdd)
        float rs[FI][4];
#pragma unroll
        for (int i = 0; i < FI; ++i)
#pragma unroll
            for (int r = 0; r < 4; ++r) rs[i][r] = 0.f;
#pragma unroll
        for (int i = 0; i < FI; ++i) {
#pragma unroll
            for (int j = 0; j < FJ; ++j) {
                int n = n0 + wc * (BN / 2) + j * 16 + fc;
                int mbase = m0 + wr * (BM / 2) + i * 16 + fr * 4;
#pragma unroll
                for (int r = 0; r < 4; ++r) {
                    float e = __expf(acc[i][j][r]);
                    ob0[(size_t)z * bss + (size_t)(mbase + r) * NN + n] = f2bf_trunc(e);
                    rs[i][r] += e;
                }
            }
        }
#pragma unroll
        for (int i = 0; i < FI; ++i) {
#pragma unroll
            for (int r = 0; r < 4; ++r) {
                float v = rs[i][r];
                v += __shfl_xor(v, 1, 16);
                v += __shfl_xor(v, 2, 16);
                v += __shfl_xor(v, 4, 16);
                v += __shfl_xor(v, 8, 16);
                if (fc == 0) {
                    int m = m0 + wr * (BM / 2) + i * 16 + fr * 4 + r;
                    atomicAdd(&outf[z * NN + m], v);
                }
            }
        }
        return;
    }

#pragma unroll
    for (int i = 0; i < FI; ++i) {
#pragma unroll
        for (int j = 0; j < FJ; ++j) {
            int n = n0 + wc * (BN / 2) + j * 16 + fc;
            int mbase = m0 + wr * (BM / 2) + i * 16 + fr * 4;
#pragma unroll
            for (int r = 0; r < 4; ++r) {
                int m = mbase + r;
                float val = acc[i][j][r];
                if constexpr (MODE == 0) {
                    val += e0[n];   // qkv bias, o = n in [0,1024)
                    if (n < 512) ob0[((size_t)z * NN + m) * NC + n] = f2bf(val * ATTN_SCALE);
                    else         ob1[((size_t)z * NN + m) * NC + (n - 512)] = f2bf(val);
                } else if constexpr (MODE == 1) {
                    val += e0[1024 + m];   // v bias, channel = m
                    ob0[((size_t)z * NC + m) * NN + n] = f2bf(val);
                } else {   // MODE 4
                    size_t idx = ((size_t)z * NC + m) * NN + n;
                    outf[idx] = val + e0[m] + e1[idx];
                }
            }
        }
    }
}

// ---------------------------------------------------------------------------
// PV GEMM: O[p,c] = (sum_m P[p,m] * V[m,c]) / L[p]
// BM=64 x BN=128, BK=64, 1024 blocks = 4 blocks/CU, XOR-swizzled LDS,
// XCD-aware 1-D block decode (unchanged from round 1 — dropped out of top-5).
// ---------------------------------------------------------------------------
__global__ __launch_bounds__(256, 4) void pv_gemm(
    const unsigned short* __restrict__ Abase,
    const unsigned short* __restrict__ Bbase,
    const float* __restrict__ L,
    unsigned short* __restrict__ Ob)
{
    // id -> (xcd, j); same-XCD ids are spaced 8 apart. c cycles fastest.
    const int id = blockIdx.x;
    const int xcd = id & 7;
    const int j0 = id >> 3;
    const int ct = j0 & 3;          // c-tile 0..3
    const int pairl = j0 >> 2;      // 0..31 per XCD
    const int p = pairl * 8 + xcd;  // 0..255 bijective
    const int ptile = p & 63, z = p >> 6;

    const size_t bss = (size_t)NN * NN, bnc = (size_t)NN * NC;
    const unsigned short* A = Abase + (size_t)z * bss;   // SP: (p, m)
    const unsigned short* B = Bbase + (size_t)z * bnc;   // V^T: (c, m)
    const int m0 = ptile * 64;
    const int n0 = ct * 128;

    __shared__ __attribute__((aligned(16))) unsigned short As[64 * 64];    // 8 KB
    __shared__ __attribute__((aligned(16))) unsigned short Bs[128 * 64];   // 16 KB

    const int t = threadIdx.x;
    const int lane = t & 63;
    const int w = t >> 6;
    const int wr = w >> 1, wc = w & 1;

    // staging: one gload round = 256 threads x 16B = 32 rows x 64 cols.
    // row&7 == lane>>3, so the pre-swizzled source slot is wave-invariant.
    const int sr = w * 8 + (lane >> 3);
    const int scs = ((lane & 7) ^ (lane >> 3)) * 8;   // pre-swizzled col (elems)
    const int lds_elem = w * 512;

    floatx4 acc[2][4] = {};

    for (int k0 = 0; k0 < NN; k0 += 64) {
#pragma unroll
        for (int s = 0; s < 2; ++s)
            gload_lds16(A + (size_t)(m0 + s * 32 + sr) * NN + k0 + scs,
                        As + s * 2048 + lds_elem);
#pragma unroll
        for (int s = 0; s < 4; ++s)
            gload_lds16(B + (size_t)(n0 + s * 32 + sr) * NN + k0 + scs,
                        Bs + s * 2048 + lds_elem);
        __syncthreads();

        bf16x8 af[2][2], bfr[4][2];
#pragma unroll
        for (int i = 0; i < 2; ++i) {
            const int ra = wr * 32 + i * 16 + (lane & 15);
#pragma unroll
            for (int kk = 0; kk < 2; ++kk)
                af[i][kk] = *(const bf16x8*)(As + ra * 64 +
                    (((kk * 4 + (lane >> 4)) ^ (ra & 7)) * 8));
        }
#pragma unroll
        for (int jj = 0; jj < 4; ++jj) {
            const int rb = wc * 64 + jj * 16 + (lane & 15);
#pragma unroll
            for (int kk = 0; kk < 2; ++kk)
                bfr[jj][kk] = *(const bf16x8*)(Bs + rb * 64 +
                    (((kk * 4 + (lane >> 4)) ^ (rb & 7)) * 8));
        }
#pragma unroll
        for (int kk = 0; kk < 2; ++kk)
#pragma unroll
            for (int i = 0; i < 2; ++i)
#pragma unroll
                for (int jj = 0; jj < 4; ++jj)
                    acc[i][jj] = __builtin_amdgcn_mfma_f32_16x16x32_bf16(
                        af[i][kk], bfr[jj][kk], acc[i][jj], 0, 0, 0);
        __syncthreads();
    }

    const int fr = lane >> 4;
    const int fc = lane & 15;
#pragma unroll
    for (int i = 0; i < 2; ++i) {
#pragma unroll
        for (int r = 0; r < 4; ++r) {
            int m = m0 + wr * 32 + i * 16 + fr * 4 + r;
            float linv = 1.0f / L[z * NN + m];
#pragma unroll
            for (int jj = 0; jj < 4; ++jj) {
                int n = n0 + wc * 64 + jj * 16 + fc;
                Ob[(size_t)z * bnc + (size_t)m * NC + n] = f2bf(acc[i][jj][r] * linv);
            }
        }
    }
}

// ---------------------------------------------------------------------------
extern "C" void kernel_launch(void* const* d_in, const int* in_sizes, int n_in,
                              void* d_out, int out_size, void* d_ws, size_t ws_size,
                              hipStream_t stream)
{
    const float* x     = (const float*)d_in[0];
    const float* gn_w  = (const float*)d_in[1];
    const float* gn_b  = (const float*)d_in[2];
    const float* qkv_w = (const float*)d_in[3];
    const float* qkv_b = (const float*)d_in[4];
    const float* out_w = (const float*)d_in[5];
    const float* out_b = (const float*)d_in[6];
    float* out = (float*)d_out;

    const size_t bnc = (size_t)NN * NC;          // 2,097,152 per batch
    char* w = (char*)d_ws;
    float* ss   = (float*)w;                 w += 16384;
    float* part = (float*)w;                 w += 8192;
    float* Lsum = (float*)w;                 w += (size_t)NB * NN * 4;  // row sums
    unsigned short* wq = (unsigned short*)w; w += (size_t)1536 * 512 * 2;
    unsigned short* wo = (unsigned short*)w; w += (size_t)512 * 512 * 2;
    unsigned short* qt = (unsigned short*)w; w += NB * bnc * 2;   // (b,n,c) pre-scaled
    unsigned short* kt = (unsigned short*)w; w += NB * bnc * 2;   // (b,n,c)
    unsigned short* vt = (unsigned short*)w; w += NB * bnc * 2;   // (b,c,n)
    unsigned short* SP = (unsigned short*)w; w += (size_t)NB * NN * NN * 2; // 128 MB
    // Aliases (lifetime-disjoint):
    unsigned short* ht = SP;   // ht (b,n,c) dead before MODE 2 writes SP
    unsigned short* Ob = qt;   // Ob (b,n,c) written after qt last read (MODE 2)

    hipMemsetAsync(Lsum, 0, (size_t)NB * NN * sizeof(float), stream);

    gn_partial_kernel<<<1024, 256, 0, stream>>>(x, part);
    gn_final_kernel<<<1, 128, 0, stream>>>(part, gn_w, gn_b, ss);
    wconv_kernel<<<(1536 * 512 + 512 * 512) / 256, 256, 0, stream>>>(qkv_w, out_w, wq, wo);
    htnorm_kernel<<<dim3(NN / 32, NC / 32, NB), 256, 0, stream>>>(x, ss, ht);

    // q/k: C[p,o] = ht · wqk^T   (q pre-scaled by ATTN_SCALE)
    mfma_gemm<0, 128, 128, 3><<<dim3(1024 / 128, NN / 128, NB), 256, 0, stream>>>(
        ht, wq, qkv_b, nullptr, nullptr, qt, kt);
    // v: C[c,p] = wv · ht^T   (64x128 tile -> 1024 blocks = 4/CU)
    mfma_gemm<1, 64, 128, 4><<<dim3(NN / 128, 512 / 64, NB), 256, 0, stream>>>(
        wq + (size_t)1024 * 512, ht, qkv_b, nullptr, nullptr, vt, nullptr);

    // QK^T + exp + row-sum accumulation, all batches, one dispatch
    mfma_gemm<2, 128, 128, 3><<<dim3(NN / 128, NN / 128, NB), 256, 0, stream>>>(
        qt, kt, nullptr, nullptr, Lsum, SP, nullptr);
    // PV + normalize, all batches, 1024 blocks (XCD-decoded inside)
    pv_gemm<<<dim3(1024), 256, 0, stream>>>(SP, vt, Lsum, Ob);

    // out projection + bias + residual (64x128 tile -> 1024 blocks = 4/CU)
    mfma_gemm<4, 64, 128, 4><<<dim3(NN / 128, 512 / 64, NB), 256, 0, stream>>>(
        wo, Ob, out_b, x, out, nullptr, nullptr);
}